// Round 4
// baseline (351.099 us; speedup 1.0000x reference)
//
#include <hip/hip_runtime.h>
#include <hip/hip_bf16.h>
#include <cstdint>
#include <cmath>

// MultiHeadAttention_38946763440365 : B=4 S=2048 D=1024 H=16 DQ=DV=64
// LN -> QKV gemm (256x256 8-phase-style, 3-buf pipelined) -> flash attention
// (swapped-QK in-register softmax, V direct-from-global) -> out gemm (+residual)
// Workspace map (bytes):
//   [0,16M)    ln    bf16 [8192][1024]   (also the residual)
//   [16M,64M)  qkv   bf16 [8192][3072]   (Q | K | V)
//   [64M,80M)  vt    bf16 [64][64][2048] (V transposed per (b,h): [dv][s])
//   [80M,96M)  ctx   bf16 [8192][1024]
//   [96M,102M) wt    bf16 [3072][1024]   (Wq^T | Wkv^T)
//   [102M,104M)wot   bf16 [1024][1024]   (Wo^T)

#define DEV static __device__ __forceinline__

typedef float  f32x4 __attribute__((ext_vector_type(4)));
typedef short  s16x8 __attribute__((ext_vector_type(8)));
typedef short  s16x4 __attribute__((ext_vector_type(4)));
typedef __bf16 bf16x8 __attribute__((ext_vector_type(8)));
typedef unsigned int u32x4 __attribute__((ext_vector_type(4)));

DEV void gload_lds16(const void* g, void* l) {
  __builtin_amdgcn_global_load_lds(
      (const __attribute__((address_space(1))) unsigned int*)g,
      (__attribute__((address_space(3))) unsigned int*)l, 16, 0, 0);
}

DEV bf16x8 ldsv(const void* p) {
  return __builtin_bit_cast(bf16x8, *(const s16x8*)p);
}

DEV f32x4 mfma16(bf16x8 a, bf16x8 b, f32x4 c) {
  return __builtin_amdgcn_mfma_f32_16x16x32_bf16(a, b, c, 0, 0, 0);
}

DEV unsigned short f2b(float f) {
  __hip_bfloat16 h = __float2bfloat16(f);
  return __builtin_bit_cast(unsigned short, h);
}

DEV unsigned int cvt_pk_bf16(float lo, float hi) {
  unsigned int r;
  asm("v_cvt_pk_bf16_f32 %0, %1, %2" : "=v"(r) : "v"(lo), "v"(hi));
  return r;
}

#define MEMFENCE asm volatile("" ::: "memory")

// ---------------------------------------------------------------- LayerNorm
__global__ __launch_bounds__(256) void ln_kernel(
    const float* __restrict__ x, const float* __restrict__ gamma,
    const float* __restrict__ beta, __hip_bfloat16* __restrict__ out)
{
  const int row = blockIdx.x, t = threadIdx.x;
  const float4 v = ((const float4*)(x + (size_t)row * 1024))[t];
  float s = v.x + v.y + v.z + v.w;
  float q = v.x * v.x + v.y * v.y + v.z * v.z + v.w * v.w;
#pragma unroll
  for (int m = 1; m < 64; m <<= 1) { s += __shfl_xor(s, m, 64); q += __shfl_xor(q, m, 64); }
  __shared__ float red[8];
  if ((t & 63) == 0) { red[t >> 6] = s; red[4 + (t >> 6)] = q; }
  __syncthreads();
  s = red[0] + red[1] + red[2] + red[3];
  q = red[4] + red[5] + red[6] + red[7];
  const float mu = s * (1.f / 1024.f);
  const float var = q * (1.f / 1024.f) - mu * mu;
  const float rs = rsqrtf(var + 1e-3f);
  const float4 g = ((const float4*)gamma)[t];
  const float4 bt = ((const float4*)beta)[t];
  s16x4 o;
  o[0] = (short)f2b((v.x - mu) * rs * g.x + bt.x);
  o[1] = (short)f2b((v.y - mu) * rs * g.y + bt.y);
  o[2] = (short)f2b((v.z - mu) * rs * g.z + bt.z);
  o[3] = (short)f2b((v.w - mu) * rs * g.w + bt.w);
  *(s16x4*)((short*)out + (size_t)row * 1024 + t * 4) = o;
}

// ------------------------------------------- weight convert + transpose (K=1024)
__global__ __launch_bounds__(256) void wconv(
    const float* __restrict__ W, int N, __hip_bfloat16* __restrict__ Wt)
{
  __shared__ float tile[64][65];
  const int t = threadIdx.x;
  const int k0 = blockIdx.x * 64, n0 = blockIdx.y * 64;
#pragma unroll
  for (int p = 0; p < 4; ++p) {
    int r = p * 16 + (t >> 4), c4 = (t & 15) * 4;
    float4 v = *(const float4*)(W + (size_t)(k0 + r) * N + n0 + c4);
    tile[r][c4] = v.x; tile[r][c4 + 1] = v.y; tile[r][c4 + 2] = v.z; tile[r][c4 + 3] = v.w;
  }
  __syncthreads();
#pragma unroll
  for (int p = 0; p < 4; ++p) {
    int n = p * 16 + (t >> 4), kc = (t & 15) * 4;
    s16x4 o;
    o[0] = (short)f2b(tile[kc][n]);     o[1] = (short)f2b(tile[kc + 1][n]);
    o[2] = (short)f2b(tile[kc + 2][n]); o[3] = (short)f2b(tile[kc + 3][n]);
    *(s16x4*)((short*)Wt + (size_t)(n0 + n) * 1024 + k0 + kc) = o;
  }
}

// -------------------------------------------- 256x256 pipelined GEMM (QKV)
// C[8192][3072] = A[8192][1024] @ Bt[3072][1024]^T + bias. BK=32, 8 waves
// (2M x 4N, per-wave 128x64), 3 LDS buffers (96KB), 2 phases/K-tile:
// {ds_read 8|4, stage 2 gload_lds, bar, prio1, 16 MFMA, prio0, [vmcnt], bar}.
// vmcnt(4) once per tile (counted, never 0 mid-loop). Lookahead = 2 K-tiles.
__global__ __launch_bounds__(512, 2) void gemm8(
    const __hip_bfloat16* __restrict__ A, const __hip_bfloat16* __restrict__ Bt,
    const float* __restrict__ bias0, const float* __restrict__ bias1, int split,
    __hip_bfloat16* __restrict__ outb)
{
  __shared__ __align__(16) short sA[3 * 8192];   // 3 x 256 rows x 32 k
  __shared__ __align__(16) short sB[3 * 8192];
  const int t = threadIdx.x, l = t & 63, w = t >> 6;
  const int wr = w >> 2, wc = w & 3, lr = l & 15, lg = l >> 4;
  // XCD-chunked bijective swizzle (gridDim.x % 8 == 0)
  int bid = blockIdx.x;
  const int cpx = gridDim.x >> 3;
  bid = (bid & 7) * cpx + (bid >> 3);
  const int bx = bid % 12, by = bid / 12;        // 12 col-tiles, 32 row-tiles
  const int row0 = by * 256, col0 = bx * 256;

  f32x4 acc[8][4] = {};
  const int NT = 32;   // 1024 / 32

  // stage one K-tile's A (or B) half: 16KB = 2 passes x 512 thr x 16B
  auto stageA = [&](int buf, int kt) {
#pragma unroll
    for (int p = 0; p < 2; ++p) {
      const int L = p * 8192 + t * 16;            // byte offset in tile
      const int r = L >> 6, c = (L >> 4) & 3;
      const int j = c ^ (r & 3);                  // pre-swizzled source chunk
      gload_lds16((const char*)A + ((size_t)(row0 + r) * 1024 + kt + j * 8) * 2,
                  (char*)sA + buf * 16384 + L);
    }
  };
  auto stageB = [&](int buf, int kt) {
#pragma unroll
    for (int p = 0; p < 2; ++p) {
      const int L = p * 8192 + t * 16;
      const int r = L >> 6, c = (L >> 4) & 3;
      const int j = c ^ (r & 3);
      gload_lds16((const char*)Bt + ((size_t)(col0 + r) * 1024 + kt + j * 8) * 2,
                  (char*)sB + buf * 16384 + L);
    }
  };

  stageA(0, 0);  stageB(0, 0);
  stageA(1, 32); stageB(1, 32);
  asm volatile("s_waitcnt vmcnt(4)" ::: "memory");
  MEMFENCE; __builtin_amdgcn_s_barrier(); MEMFENCE;

#pragma unroll 1
  for (int ti = 0; ti < NT; ++ti) {
    const int cur = ti % 3, nx2 = (ti + 2) % 3;
    const char* bA = (const char*)sA + cur * 16384;
    const char* bB = (const char*)sB + cur * 16384;
    // ---- phase 0: B-frags + A-frags mb0-3, stage A(t+2), 16 MFMA
    bf16x8 bfr[4], af[4];
#pragma unroll
    for (int nb = 0; nb < 4; ++nb) {
      const int br = wc * 64 + nb * 16 + lr;
      bfr[nb] = ldsv(bB + br * 64 + ((lg ^ (br & 3)) * 16));
    }
#pragma unroll
    for (int mb = 0; mb < 4; ++mb) {
      const int ar = wr * 128 + mb * 16 + lr;
      af[mb] = ldsv(bA + ar * 64 + ((lg ^ (ar & 3)) * 16));
    }
    if (ti + 2 < NT) stageA(nx2, (ti + 2) * 32);
    MEMFENCE; __builtin_amdgcn_s_barrier(); MEMFENCE;
    __builtin_amdgcn_s_setprio(1);
#pragma unroll
    for (int mb = 0; mb < 4; ++mb)
#pragma unroll
      for (int nb = 0; nb < 4; ++nb)
        acc[mb][nb] = mfma16(af[mb], bfr[nb], acc[mb][nb]);
    __builtin_amdgcn_s_setprio(0);
    MEMFENCE; __builtin_amdgcn_s_barrier(); MEMFENCE;
    // ---- phase 1: A-frags mb4-7, stage B(t+2), 16 MFMA
#pragma unroll
    for (int mb = 0; mb < 4; ++mb) {
      const int ar = wr * 128 + 64 + mb * 16 + lr;
      af[mb] = ldsv(bA + ar * 64 + ((lg ^ (ar & 3)) * 16));
    }
    if (ti + 2 < NT) stageB(nx2, (ti + 2) * 32);
    MEMFENCE; __builtin_amdgcn_s_barrier(); MEMFENCE;
    __builtin_amdgcn_s_setprio(1);
#pragma unroll
    for (int mb = 0; mb < 4; ++mb)
#pragma unroll
      for (int nb = 0; nb < 4; ++nb)
        acc[mb + 4][nb] = mfma16(af[mb], bfr[nb], acc[mb + 4][nb]);
    __builtin_amdgcn_s_setprio(0);
    // tile t+1 must be fully landed before next iteration reads it
    if (ti + 2 < NT) asm volatile("s_waitcnt vmcnt(4)" ::: "memory");
    else             asm volatile("s_waitcnt vmcnt(0)" ::: "memory");
    MEMFENCE; __builtin_amdgcn_s_barrier(); MEMFENCE;
  }

#pragma unroll
  for (int mb = 0; mb < 8; ++mb) {
    const int rbase = row0 + wr * 128 + mb * 16 + lg * 4;
#pragma unroll
    for (int nb = 0; nb < 4; ++nb) {
      const int col = col0 + wc * 64 + nb * 16 + lr;
      const float bias = (col < split) ? bias0[col] : bias1[col - split];
#pragma unroll
      for (int jr = 0; jr < 4; ++jr)
        outb[(size_t)(rbase + jr) * 3072 + col] = __float2bfloat16(acc[mb][nb][jr] + bias);
    }
  }
}

// ------------------------------------------------------- GEMM: C = A @ Bt^T (out proj)
__global__ __launch_bounds__(256, 2) void gemm_bt(
    const __hip_bfloat16* __restrict__ A, const __hip_bfloat16* __restrict__ Bt,
    const float* __restrict__ bias0,
    const __hip_bfloat16* __restrict__ resid, float* __restrict__ outf)
{
  __shared__ __align__(16) short sA[128 * 64];
  __shared__ __align__(16) short sB[128 * 64];
  const int t = threadIdx.x, l = t & 63, w = t >> 6;
  const int wr = w >> 1, wc = w & 1, lr = l & 15, lg = l >> 4;
  const int row0 = blockIdx.y * 128, col0 = blockIdx.x * 128;
  f32x4 acc[4][4] = {};

  for (int kt = 0; kt < 1024; kt += 64) {
#pragma unroll
    for (int p = 0; p < 4; ++p) {
      const int L = p * 4096 + t * 16;
      const int r = L >> 7, c = ((L >> 4) & 7) ^ (r & 7);
      gload_lds16((const char*)A + ((size_t)(row0 + r) * 1024 + kt + c * 8) * 2, (char*)sA + L);
    }
#pragma unroll
    for (int p = 0; p < 4; ++p) {
      const int L = p * 4096 + t * 16;
      const int r = L >> 7, c = ((L >> 4) & 7) ^ (r & 7);
      gload_lds16((const char*)Bt + ((size_t)(col0 + r) * 1024 + kt + c * 8) * 2, (char*)sB + L);
    }
    __syncthreads();

    bf16x8 af[4][2], bfr[4][2];
#pragma unroll
    for (int mb = 0; mb < 4; ++mb) {
      const int ar = wr * 64 + mb * 16 + lr;
#pragma unroll
      for (int kk = 0; kk < 2; ++kk)
        af[mb][kk] = ldsv((const char*)sA + ar * 128 + (((kk * 4 + lg) ^ (ar & 7)) * 16));
    }
#pragma unroll
    for (int nb = 0; nb < 4; ++nb) {
      const int br = wc * 64 + nb * 16 + lr;
#pragma unroll
      for (int kk = 0; kk < 2; ++kk)
        bfr[nb][kk] = ldsv((const char*)sB + br * 128 + (((kk * 4 + lg) ^ (br & 7)) * 16));
    }
#pragma unroll
    for (int kk = 0; kk < 2; ++kk)
#pragma unroll
      for (int mb = 0; mb < 4; ++mb)
#pragma unroll
        for (int nb = 0; nb < 4; ++nb)
          acc[mb][nb] = mfma16(af[mb][kk], bfr[nb][kk], acc[mb][nb]);
    __syncthreads();
  }

#pragma unroll
  for (int mb = 0; mb < 4; ++mb) {
    const int rbase = row0 + wr * 64 + mb * 16 + lg * 4;
#pragma unroll
    for (int nb = 0; nb < 4; ++nb) {
      const int col = col0 + wc * 64 + nb * 16 + lr;
      const float bias = bias0[col];
#pragma unroll
      for (int jr = 0; jr < 4; ++jr) {
        const size_t idx = (size_t)(rbase + jr) * 1024 + col;
        outf[idx] = acc[mb][nb][jr] + bias + __bfloat162float(resid[idx]);
      }
    }
  }
}

// --------------------------------------- V transpose: qkv V-part -> [bh][dv][s]
__global__ __launch_bounds__(256) void vtrans(
    const __hip_bfloat16* __restrict__ qkv, __hip_bfloat16* __restrict__ vt)
{
  __shared__ __align__(16) short tile[64][72];
  const int t = threadIdx.x;
  const int s0 = blockIdx.x * 64;
  const int bh = blockIdx.y, b = bh >> 4, h = bh & 15;
#pragma unroll
  for (int p = 0; p < 2; ++p) {
    int idx = p * 256 + t;
    int r = idx >> 3, c = idx & 7;
    s16x8 vv = *(const s16x8*)((const short*)qkv +
        (size_t)(b * 2048 + s0 + r) * 3072 + 2048 + h * 64 + c * 8);
    *(s16x8*)((char*)tile + r * 144 + c * 16) = vv;
  }
  __syncthreads();
  const int dv = t >> 2, sc = (t & 3) * 16;
  s16x8 a, bvec;
#pragma unroll
  for (int e = 0; e < 8; ++e) a[e] = tile[sc + e][dv];
#pragma unroll
  for (int e = 0; e < 8; ++e) bvec[e] = tile[sc + 8 + e][dv];
  short* dst = (short*)vt + (size_t)(bh * 64 + dv) * 2048 + s0 + sc;
  *(s16x8*)dst = a;
  *(s16x8*)(dst + 8) = bvec;
}

// ----------------------------------------------------------- flash attention
// grid 2048 blocks (swizzled); 4 waves x 16 q-rows; KVBLK=64.
// Swapped QK^T (in-register softmax, log2 domain, defer-rescale). K double-
// buffered in LDS (16KB); V^T fragments loaded DIRECTLY from global (issued
// early, latency hidden under QK^T+softmax).
__global__ __launch_bounds__(256, 4) void attn_kernel(
    const __hip_bfloat16* __restrict__ qkv, const __hip_bfloat16* __restrict__ vt,
    const int* __restrict__ lens, __hip_bfloat16* __restrict__ ctx)
{
  __shared__ __align__(16) short sK[2][64 * 64];
  const int t = threadIdx.x, l = t & 63, w = t >> 6;
  const int lr = l & 15, lg = l >> 4;
  // XCD-chunked swizzle so same-bh blocks co-locate per XCD (2048 % 8 == 0)
  int bid = blockIdx.x;
  bid = (bid & 7) * 256 + (bid >> 3);
  const int qb = bid & 31, bh = bid >> 5, b = bh >> 4, h = bh & 15;
  const int q0w = qb * 64 + w * 16;
  const int len = lens[b];
  const float NEG = -__builtin_inff();
  const float QSC = 0.18033688f;  // 0.125 * log2(e)

  // Q fragments (B-operand: lane holds q = lr, d = kk*32 + lg*8 + e)
  bf16x8 qf[2];
#pragma unroll
  for (int kk = 0; kk < 2; ++kk) {
    bf16x8 r = ldsv((const char*)qkv +
        ((size_t)(b * 2048 + q0w + lr) * 3072 + h * 64 + kk * 32 + lg * 8) * 2);
#pragma unroll
    for (int e = 0; e < 8; ++e) qf[kk][e] = (__bf16)((float)r[e] * QSC);
  }

  // o[nbt2] = O^T: lane holds q = lr, dv = nbt2*16 + lg*4 + jr
  f32x4 o[4] = {};
  float mrun = NEG, ssum = 0.f;

  auto stageK = [&](short* dK, int kv0) {
#pragma unroll
    for (int p = 0; p < 2; ++p) {
      const int L = p * 4096 + t * 16;
      const int r = L >> 7, c = ((L >> 4) & 7) ^ (r & 7);
      gload_lds16((const char*)qkv +
          ((size_t)(b * 2048 + kv0 + r) * 3072 + 1024 + h * 64 + c * 8) * 2, (char*)dK + L);
    }
  };

  const int nt = (len + 63) >> 6;
  short* curK = sK[0]; short* nxtK = sK[1];
  stageK(curK, 0);

  const int srcA = (lg & 1) * 32 + lr;
  const int srcB = srcA + 16;

  for (int ti = 0; ti < nt; ++ti) {
    const int kv0 = ti * 64;
    if (ti + 1 < nt) {
      stageK(nxtK, kv0 + 64);
      asm volatile("s_waitcnt vmcnt(2)" ::: "memory");
    } else {
      asm volatile("s_waitcnt vmcnt(0)" ::: "memory");
    }
    MEMFENCE; __builtin_amdgcn_s_barrier(); MEMFENCE;

    // ---- V^T fragments direct from global (used only in PV -> latency hidden)
    bf16x8 vf[4][2];
#pragma unroll
    for (int nbt2 = 0; nbt2 < 4; ++nbt2)
#pragma unroll
      for (int c = 0; c < 2; ++c)
        vf[nbt2][c] = ldsv((const char*)vt +
            ((size_t)(bh * 64 + nbt2 * 16 + lr) * 2048 + kv0 + (c * 4 + lg) * 8) * 2);

    // ---- S^T = mfma(K, Q): lane (lr,lg): q = lr, kv = nbt*16 + lg*4 + jr
    f32x4 sf[4] = {};
    __builtin_amdgcn_s_setprio(1);
#pragma unroll
    for (int kk = 0; kk < 2; ++kk) {
      bf16x8 ak[4];
#pragma unroll
      for (int nbt = 0; nbt < 4; ++nbt) {
        const int br = nbt * 16 + lr;
        ak[nbt] = ldsv((const char*)curK + br * 128 + (((kk * 4 + lg) ^ (br & 7)) * 16));
      }
#pragma unroll
      for (int nbt = 0; nbt < 4; ++nbt)
        sf[nbt] = mfma16(ak[nbt], qf[kk], sf[nbt]);
    }
    __builtin_amdgcn_s_setprio(0);

    if (kv0 + 64 > len) {
#pragma unroll
      for (int nbt = 0; nbt < 4; ++nbt)
#pragma unroll
        for (int jr = 0; jr < 4; ++jr)
          if (kv0 + nbt * 16 + lg * 4 + jr >= len) sf[nbt][jr] = NEG;
    }

    // ---- in-register online softmax (defer-rescale THR=3)
    f32x4 m4 = sf[0];
    m4 = __builtin_elementwise_max(m4, sf[1]);
    m4 = __builtin_elementwise_max(m4, sf[2]);
    m4 = __builtin_elementwise_max(m4, sf[3]);
    float rm = fmaxf(fmaxf(m4[0], m4[1]), fmaxf(m4[2], m4[3]));
    rm = fmaxf(rm, __shfl_xor(rm, 16, 64));
    rm = fmaxf(rm, __shfl_xor(rm, 32, 64));
    if (__any(rm > mrun + 3.f)) {
      const float mnew = fmaxf(mrun, rm);
      const float corr = __builtin_amdgcn_exp2f(mrun - mnew);
      mrun = mnew;
      ssum *= corr;
#pragma unroll
      for (int nbt2 = 0; nbt2 < 4; ++nbt2) o[nbt2] *= corr;
    }
    unsigned int W0[4], W1[4];
    {
      f32x4 ts = {0.f, 0.f, 0.f, 0.f};
#pragma unroll
      for (int nbt = 0; nbt < 4; ++nbt) {
        f32x4 pe;
#pragma unroll
        for (int jr = 0; jr < 4; ++jr)
          pe[jr] = __builtin_amdgcn_exp2f(sf[nbt][jr] - mrun);
        ts += pe;
        W0[nbt] = cvt_pk_bf16(pe[0], pe[1]);
        W1[nbt] = cvt_pk_bf16(pe[2], pe[3]);
      }
      ssum += (ts[0] + ts[1]) + (ts[2] + ts[3]);
    }

    // ---- PV: O^T += mfma(A=V^T, B=P)
#pragma unroll
    for (int c = 0; c < 2; ++c) {
      const unsigned int selW0 = (lg & 2) ? W0[2 * c + 1] : W0[2 * c];
      const unsigned int selW1 = (lg & 2) ? W1[2 * c + 1] : W1[2 * c];
      u32x4 bw;
      bw[0] = __shfl((int)selW0, srcA, 64);
      bw[1] = __shfl((int)selW1, srcA, 64);
      bw[2] = __shfl((int)selW0, srcB, 64);
      bw[3] = __shfl((int)selW1, srcB, 64);
      const bf16x8 pb = __builtin_bit_cast(bf16x8, bw);
      __builtin_amdgcn_s_setprio(1);
#pragma unroll
      for (int nbt2 = 0; nbt2 < 4; ++nbt2)
        o[nbt2] = mfma16(vf[nbt2][c], pb, o[nbt2]);
      __builtin_amdgcn_s_setprio(0);
    }

    asm volatile("s_waitcnt lgkmcnt(0)" ::: "memory");
    MEMFENCE; __builtin_amdgcn_s_barrier(); MEMFENCE;
    short* tk = curK; curK = nxtK; nxtK = tk;
  }

  // ---- epilogue: normalize, transpose O^T -> O via LDS bounce, coalesced store
  float s = ssum;
  s += __shfl_xor(s, 16, 64);
  s += __shfl_xor(s, 32, 64);
  const float inv = 1.f / s;
  char* eb = (char*)sK + w * 2176;   // 16 rows x 68 shorts (136 B stride)
#pragma unroll
  for (int nbt2 = 0; nbt2 < 4; ++nbt2)
#pragma unroll
    for (int jr = 0; jr < 4; ++jr)
      *(short*)(eb + lr * 136 + (nbt2 * 16 + lg * 4 + jr) * 2) =
          (short)f2b(o[nbt2][jr] * inv);
  asm volatile("s_waitcnt lgkmcnt(0)" ::: "memory");
  __builtin_amdgcn_sched_barrier(0);
  const int qi = l >> 2, pt = l & 3;
#pragma unroll
  for (int i = 0; i < 2; ++i) {
    const int ch = pt * 2 + i;
    s16x8 v = *(const s16x8*)(eb + qi * 136 + ch * 16);
    *(s16x8*)((short*)ctx + (size_t)(b * 2048 + q0w + qi) * 1024 + h * 64 + ch * 8) = v;
  }
}

// ------------------------------------------------------------------- launch
extern "C" void kernel_launch(void* const* d_in, const int* in_sizes, int n_in,
                              void* d_out, int out_size, void* d_ws, size_t ws_size,
                              hipStream_t stream)
{
  const float* x     = (const float*)d_in[0];
  const int*   lens  = (const int*)d_in[2];
  const float* Wq    = (const float*)d_in[3];
  const float* bq    = (const float*)d_in[4];
  const float* Wkv   = (const float*)d_in[5];
  const float* bkv   = (const float*)d_in[6];
  const float* Wo    = (const float*)d_in[7];
  const float* bo    = (const float*)d_in[8];
  const float* gamma = (const float*)d_in[9];
  const float* beta  = (const float*)d_in[10];
  float* out = (float*)d_out;

  char* ws = (char*)d_ws;
  __hip_bfloat16* ln  = (__hip_bfloat16*)(ws);
  __hip_bfloat16* qkv = (__hip_bfloat16*)(ws + ((size_t)16 << 20));
  __hip_bfloat16* vt  = (__hip_bfloat16*)(ws + ((size_t)64 << 20));
  __hip_bfloat16* ctx = (__hip_bfloat16*)(ws + ((size_t)80 << 20));
  __hip_bfloat16* wt  = (__hip_bfloat16*)(ws + ((size_t)96 << 20));
  __hip_bfloat16* wot = (__hip_bfloat16*)(ws + ((size_t)102 << 20));

  ln_kernel<<<dim3(8192), dim3(256), 0, stream>>>(x, gamma, beta, ln);
  wconv<<<dim3(16, 16), dim3(256), 0, stream>>>(Wq, 1024, wt);
  wconv<<<dim3(16, 32), dim3(256), 0, stream>>>(Wkv, 2048, wt + (size_t)1024 * 1024);
  wconv<<<dim3(16, 16), dim3(256), 0, stream>>>(Wo, 1024, wot);
  gemm8<<<dim3(384), dim3(512), 0, stream>>>(ln, wt, bq, bkv, 1024, qkv);
  vtrans<<<dim3(32, 64), dim3(256), 0, stream>>>(qkv, vt);
  attn_kernel<<<dim3(2048), dim3(256), 0, stream>>>(qkv, vt, lens, ctx);
  gemm_bt<<<dim3(8, 64), dim3(256), 0, stream>>>(ctx, wot, bo, ln, out);
}

// Round 5
// 188.926 us; speedup vs baseline: 1.8584x; 1.8584x over previous
//
#include <hip/hip_runtime.h>
#include <hip/hip_bf16.h>
#include <cstdint>
#include <cmath>

// MultiHeadAttention_38946763440365 : B=4 S=2048 D=1024 H=16 DQ=DV=64
// LN -> QKV gemm (256x256 pipelined) -> flash attention (swapped-QK in-register
// softmax, K/V dbuf in LDS) -> out gemm (+bias+residual)
// Workspace map (bytes):
//   [0,16M)    ln    bf16 [8192][1024]   (also the residual)
//   [16M,64M)  qkv   bf16 [8192][3072]   (Q | K | V)
//   [64M,80M)  vt    bf16 [64][64][2048] (V transposed per (b,h): [dv][s])
//   [80M,96M)  ctx   bf16 [8192][1024]
//   [96M,102M) wt    bf16 [3072][1024]   (Wq^T | Wkv^T)
//   [102M,104M)wot   bf16 [1024][1024]   (Wo^T)

#define DEV static __device__ __forceinline__

typedef float  f32x4 __attribute__((ext_vector_type(4)));
typedef short  s16x8 __attribute__((ext_vector_type(8)));
typedef short  s16x4 __attribute__((ext_vector_type(4)));
typedef __bf16 bf16x8 __attribute__((ext_vector_type(8)));
typedef unsigned int u32x4 __attribute__((ext_vector_type(4)));

DEV void gload_lds16(const void* g, void* l) {
  __builtin_amdgcn_global_load_lds(
      (const __attribute__((address_space(1))) unsigned int*)g,
      (__attribute__((address_space(3))) unsigned int*)l, 16, 0, 0);
}

DEV bf16x8 ldsv(const void* p) {
  return __builtin_bit_cast(bf16x8, *(const s16x8*)p);
}

DEV f32x4 mfma16(bf16x8 a, bf16x8 b, f32x4 c) {
  return __builtin_amdgcn_mfma_f32_16x16x32_bf16(a, b, c, 0, 0, 0);
}

DEV unsigned short f2b(float f) {
  __hip_bfloat16 h = __float2bfloat16(f);
  return __builtin_bit_cast(unsigned short, h);
}

DEV unsigned int cvt_pk_bf16(float lo, float hi) {
  unsigned int r;
  asm("v_cvt_pk_bf16_f32 %0, %1, %2" : "=v"(r) : "v"(lo), "v"(hi));
  return r;
}

#define MEMFENCE asm volatile("" ::: "memory")

// ---------------------------------------------------------------- LayerNorm
__global__ __launch_bounds__(256) void ln_kernel(
    const float* __restrict__ x, const float* __restrict__ gamma,
    const float* __restrict__ beta, __hip_bfloat16* __restrict__ out)
{
  const int row = blockIdx.x, t = threadIdx.x;
  const float4 v = ((const float4*)(x + (size_t)row * 1024))[t];
  float s = v.x + v.y + v.z + v.w;
  float q = v.x * v.x + v.y * v.y + v.z * v.z + v.w * v.w;
#pragma unroll
  for (int m = 1; m < 64; m <<= 1) { s += __shfl_xor(s, m, 64); q += __shfl_xor(q, m, 64); }
  __shared__ float red[8];
  if ((t & 63) == 0) { red[t >> 6] = s; red[4 + (t >> 6)] = q; }
  __syncthreads();
  s = red[0] + red[1] + red[2] + red[3];
  q = red[4] + red[5] + red[6] + red[7];
  const float mu = s * (1.f / 1024.f);
  const float var = q * (1.f / 1024.f) - mu * mu;
  const float rs = rsqrtf(var + 1e-3f);
  const float4 g = ((const float4*)gamma)[t];
  const float4 bt = ((const float4*)beta)[t];
  s16x4 o;
  o[0] = (short)f2b((v.x - mu) * rs * g.x + bt.x);
  o[1] = (short)f2b((v.y - mu) * rs * g.y + bt.y);
  o[2] = (short)f2b((v.z - mu) * rs * g.z + bt.z);
  o[3] = (short)f2b((v.w - mu) * rs * g.w + bt.w);
  *(s16x4*)((short*)out + (size_t)row * 1024 + t * 4) = o;
}

// ------------------------------------------- weight convert + transpose (K=1024)
__global__ __launch_bounds__(256) void wconv(
    const float* __restrict__ W, int N, __hip_bfloat16* __restrict__ Wt)
{
  __shared__ float tile[64][65];
  const int t = threadIdx.x;
  const int k0 = blockIdx.x * 64, n0 = blockIdx.y * 64;
#pragma unroll
  for (int p = 0; p < 4; ++p) {
    int r = p * 16 + (t >> 4), c4 = (t & 15) * 4;
    float4 v = *(const float4*)(W + (size_t)(k0 + r) * N + n0 + c4);
    tile[r][c4] = v.x; tile[r][c4 + 1] = v.y; tile[r][c4 + 2] = v.z; tile[r][c4 + 3] = v.w;
  }
  __syncthreads();
#pragma unroll
  for (int p = 0; p < 4; ++p) {
    int n = p * 16 + (t >> 4), kc = (t & 15) * 4;
    s16x4 o;
    o[0] = (short)f2b(tile[kc][n]);     o[1] = (short)f2b(tile[kc + 1][n]);
    o[2] = (short)f2b(tile[kc + 2][n]); o[3] = (short)f2b(tile[kc + 3][n]);
    *(s16x4*)((short*)Wt + (size_t)(n0 + n) * 1024 + k0 + kc) = o;
  }
}

// -------------------------------------------- 256x256 pipelined GEMM (QKV)
__global__ __launch_bounds__(512, 2) void gemm8(
    const __hip_bfloat16* __restrict__ A, const __hip_bfloat16* __restrict__ Bt,
    const float* __restrict__ bias0, const float* __restrict__ bias1, int split,
    __hip_bfloat16* __restrict__ outb)
{
  __shared__ __align__(16) short sA[3 * 8192];   // 3 x 256 rows x 32 k
  __shared__ __align__(16) short sB[3 * 8192];
  const int t = threadIdx.x, l = t & 63, w = t >> 6;
  const int wr = w >> 2, wc = w & 3, lr = l & 15, lg = l >> 4;
  int bid = blockIdx.x;
  const int cpx = gridDim.x >> 3;
  bid = (bid & 7) * cpx + (bid >> 3);
  const int bx = bid % 12, by = bid / 12;        // 12 col-tiles, 32 row-tiles
  const int row0 = by * 256, col0 = bx * 256;

  f32x4 acc[8][4] = {};
  const int NT = 32;   // 1024 / 32

  auto stageA = [&](int buf, int kt) {
#pragma unroll
    for (int p = 0; p < 2; ++p) {
      const int L = p * 8192 + t * 16;
      const int r = L >> 6, c = (L >> 4) & 3;
      const int j = c ^ (r & 3);
      gload_lds16((const char*)A + ((size_t)(row0 + r) * 1024 + kt + j * 8) * 2,
                  (char*)sA + buf * 16384 + L);
    }
  };
  auto stageB = [&](int buf, int kt) {
#pragma unroll
    for (int p = 0; p < 2; ++p) {
      const int L = p * 8192 + t * 16;
      const int r = L >> 6, c = (L >> 4) & 3;
      const int j = c ^ (r & 3);
      gload_lds16((const char*)Bt + ((size_t)(col0 + r) * 1024 + kt + j * 8) * 2,
                  (char*)sB + buf * 16384 + L);
    }
  };

  stageA(0, 0);  stageB(0, 0);
  stageA(1, 32); stageB(1, 32);
  asm volatile("s_waitcnt vmcnt(4)" ::: "memory");
  MEMFENCE; __builtin_amdgcn_s_barrier(); MEMFENCE;

#pragma unroll 1
  for (int ti = 0; ti < NT; ++ti) {
    const int cur = ti % 3, nx2 = (ti + 2) % 3;
    const char* bA = (const char*)sA + cur * 16384;
    const char* bB = (const char*)sB + cur * 16384;
    bf16x8 bfr[4], af[4];
#pragma unroll
    for (int nb = 0; nb < 4; ++nb) {
      const int br = wc * 64 + nb * 16 + lr;
      bfr[nb] = ldsv(bB + br * 64 + ((lg ^ (br & 3)) * 16));
    }
#pragma unroll
    for (int mb = 0; mb < 4; ++mb) {
      const int ar = wr * 128 + mb * 16 + lr;
      af[mb] = ldsv(bA + ar * 64 + ((lg ^ (ar & 3)) * 16));
    }
    if (ti + 2 < NT) stageA(nx2, (ti + 2) * 32);
    MEMFENCE; __builtin_amdgcn_s_barrier(); MEMFENCE;
    __builtin_amdgcn_s_setprio(1);
#pragma unroll
    for (int mb = 0; mb < 4; ++mb)
#pragma unroll
      for (int nb = 0; nb < 4; ++nb)
        acc[mb][nb] = mfma16(af[mb], bfr[nb], acc[mb][nb]);
    __builtin_amdgcn_s_setprio(0);
    MEMFENCE; __builtin_amdgcn_s_barrier(); MEMFENCE;
#pragma unroll
    for (int mb = 0; mb < 4; ++mb) {
      const int ar = wr * 128 + 64 + mb * 16 + lr;
      af[mb] = ldsv(bA + ar * 64 + ((lg ^ (ar & 3)) * 16));
    }
    if (ti + 2 < NT) stageB(nx2, (ti + 2) * 32);
    MEMFENCE; __builtin_amdgcn_s_barrier(); MEMFENCE;
    __builtin_amdgcn_s_setprio(1);
#pragma unroll
    for (int mb = 0; mb < 4; ++mb)
#pragma unroll
      for (int nb = 0; nb < 4; ++nb)
        acc[mb + 4][nb] = mfma16(af[mb], bfr[nb], acc[mb + 4][nb]);
    __builtin_amdgcn_s_setprio(0);
    if (ti + 2 < NT) asm volatile("s_waitcnt vmcnt(4)" ::: "memory");
    else             asm volatile("s_waitcnt vmcnt(0)" ::: "memory");
    MEMFENCE; __builtin_amdgcn_s_barrier(); MEMFENCE;
  }

#pragma unroll
  for (int mb = 0; mb < 8; ++mb) {
    const int rbase = row0 + wr * 128 + mb * 16 + lg * 4;
#pragma unroll
    for (int nb = 0; nb < 4; ++nb) {
      const int col = col0 + wc * 64 + nb * 16 + lr;
      const float bias = (col < split) ? bias0[col] : bias1[col - split];
#pragma unroll
      for (int jr = 0; jr < 4; ++jr)
        outb[(size_t)(rbase + jr) * 3072 + col] = __float2bfloat16(acc[mb][nb][jr] + bias);
    }
  }
}

// ------------------------------------------------------- GEMM: out proj (+resid)
__global__ __launch_bounds__(256, 2) void gemm_bt(
    const __hip_bfloat16* __restrict__ A, const __hip_bfloat16* __restrict__ Bt,
    const float* __restrict__ bias0,
    const __hip_bfloat16* __restrict__ resid, float* __restrict__ outf)
{
  __shared__ __align__(16) short sA[128 * 64];
  __shared__ __align__(16) short sB[128 * 64];
  const int t = threadIdx.x, l = t & 63, w = t >> 6;
  const int wr = w >> 1, wc = w & 1, lr = l & 15, lg = l >> 4;
  const int row0 = blockIdx.y * 128, col0 = blockIdx.x * 128;
  f32x4 acc[4][4] = {};

  for (int kt = 0; kt < 1024; kt += 64) {
#pragma unroll
    for (int p = 0; p < 4; ++p) {
      const int L = p * 4096 + t * 16;
      const int r = L >> 7, c = ((L >> 4) & 7) ^ (r & 7);
      gload_lds16((const char*)A + ((size_t)(row0 + r) * 1024 + kt + c * 8) * 2, (char*)sA + L);
    }
#pragma unroll
    for (int p = 0; p < 4; ++p) {
      const int L = p * 4096 + t * 16;
      const int r = L >> 7, c = ((L >> 4) & 7) ^ (r & 7);
      gload_lds16((const char*)Bt + ((size_t)(col0 + r) * 1024 + kt + c * 8) * 2, (char*)sB + L);
    }
    __syncthreads();

    bf16x8 af[4][2], bfr[4][2];
#pragma unroll
    for (int mb = 0; mb < 4; ++mb) {
      const int ar = wr * 64 + mb * 16 + lr;
#pragma unroll
      for (int kk = 0; kk < 2; ++kk)
        af[mb][kk] = ldsv((const char*)sA + ar * 128 + (((kk * 4 + lg) ^ (ar & 7)) * 16));
    }
#pragma unroll
    for (int nb = 0; nb < 4; ++nb) {
      const int br = wc * 64 + nb * 16 + lr;
#pragma unroll
      for (int kk = 0; kk < 2; ++kk)
        bfr[nb][kk] = ldsv((const char*)sB + br * 128 + (((kk * 4 + lg) ^ (br & 7)) * 16));
    }
#pragma unroll
    for (int kk = 0; kk < 2; ++kk)
#pragma unroll
      for (int mb = 0; mb < 4; ++mb)
#pragma unroll
        for (int nb = 0; nb < 4; ++nb)
          acc[mb][nb] = mfma16(af[mb][kk], bfr[nb][kk], acc[mb][nb]);
    __syncthreads();
  }

#pragma unroll
  for (int mb = 0; mb < 4; ++mb) {
    const int rbase = row0 + wr * 64 + mb * 16 + lg * 4;
#pragma unroll
    for (int nb = 0; nb < 4; ++nb) {
      const int col = col0 + wc * 64 + nb * 16 + lr;
      const float bias = bias0[col];
#pragma unroll
      for (int jr = 0; jr < 4; ++jr) {
        const size_t idx = (size_t)(rbase + jr) * 1024 + col;
        outf[idx] = acc[mb][nb][jr] + bias + __bfloat162float(resid[idx]);
      }
    }
  }
}

// --------------------------------------- V transpose: qkv V-part -> [bh][dv][s]
__global__ __launch_bounds__(256) void vtrans(
    const __hip_bfloat16* __restrict__ qkv, __hip_bfloat16* __restrict__ vt)
{
  __shared__ __align__(16) short tile[64][72];
  const int t = threadIdx.x;
  const int s0 = blockIdx.x * 64;
  const int bh = blockIdx.y, b = bh >> 4, h = bh & 15;
#pragma unroll
  for (int p = 0; p < 2; ++p) {
    int idx = p * 256 + t;
    int r = idx >> 3, c = idx & 7;
    s16x8 vv = *(const s16x8*)((const short*)qkv +
        (size_t)(b * 2048 + s0 + r) * 3072 + 2048 + h * 64 + c * 8);
    *(s16x8*)((char*)tile + r * 144 + c * 16) = vv;
  }
  __syncthreads();
  const int dv = t >> 2, sc = (t & 3) * 16;
  s16x8 a, bvec;
#pragma unroll
  for (int e = 0; e < 8; ++e) a[e] = tile[sc + e][dv];
#pragma unroll
  for (int e = 0; e < 8; ++e) bvec[e] = tile[sc + 8 + e][dv];
  short* dst = (short*)vt + (size_t)(bh * 64 + dv) * 2048 + s0 + sc;
  *(s16x8*)dst = a;
  *(s16x8*)(dst + 8) = bvec;
}

// ----------------------------------------------------------- flash attention
// grid (S/128, B*H); 4 waves x 32 q-rows; KVBLK=64. (R3-verified structure)
// Swapped QK^T: S^T = mfma(K, Q), softmax fully in-register; PV B-frag via
// cvt_pk + shfl; K/V double-buffered in LDS; O^T bounced through LDS at end.
__global__ __launch_bounds__(256, 4) void attn_kernel(
    const __hip_bfloat16* __restrict__ qkv, const __hip_bfloat16* __restrict__ vt,
    const int* __restrict__ lens, __hip_bfloat16* __restrict__ ctx)
{
  __shared__ __align__(16) short sK[2][64 * 64];
  __shared__ __align__(16) short sV[2][64 * 64];
  const int t = threadIdx.x, l = t & 63, w = t >> 6;
  const int lr = l & 15, lg = l >> 4;
  const int bh = blockIdx.y, b = bh >> 4, h = bh & 15;
  const int q0 = blockIdx.x * 128 + w * 32;
  const int len = lens[b];
  const float NEG = -__builtin_inff();
  const float QSC = 0.18033688f;  // 0.125 * log2(e)

  bf16x8 qf[2][2];
#pragma unroll
  for (int mbt = 0; mbt < 2; ++mbt)
#pragma unroll
    for (int kk = 0; kk < 2; ++kk) {
      bf16x8 r = ldsv((const char*)qkv +
          ((size_t)(b * 2048 + q0 + mbt * 16 + lr) * 3072 + h * 64 + kk * 32 + lg * 8) * 2);
#pragma unroll
      for (int e = 0; e < 8; ++e) qf[mbt][kk][e] = (__bf16)((float)r[e] * QSC);
    }

  f32x4 o[4][2] = {};
  float mrun[2] = {NEG, NEG}, ssum[2] = {0.f, 0.f};

  auto stage = [&](short* dK, short* dV, int kv0) {
#pragma unroll
    for (int p = 0; p < 2; ++p) {
      const int L = p * 4096 + t * 16;
      const int r = L >> 7, c = ((L >> 4) & 7) ^ (r & 7);
      gload_lds16((const char*)qkv +
          ((size_t)(b * 2048 + kv0 + r) * 3072 + 1024 + h * 64 + c * 8) * 2, (char*)dK + L);
    }
#pragma unroll
    for (int p = 0; p < 2; ++p) {
      const int L = p * 4096 + t * 16;
      const int r = L >> 7, c = ((L >> 4) & 7) ^ (r & 7);
      gload_lds16((const char*)vt +
          ((size_t)(bh * 64 + r) * 2048 + kv0 + c * 8) * 2, (char*)dV + L);
    }
  };

  const int nt = (len + 63) >> 6;
  short* curK = sK[0]; short* nxtK = sK[1];
  short* curV = sV[0]; short* nxtV = sV[1];
  stage(curK, curV, 0);

  const int srcA = (lg & 1) * 32 + lr;
  const int srcB = srcA + 16;

  for (int ti = 0; ti < nt; ++ti) {
    const int kv0 = ti * 64;
    if (ti + 1 < nt) {
      stage(nxtK, nxtV, kv0 + 64);
      asm volatile("s_waitcnt vmcnt(4)" ::: "memory");
    } else {
      asm volatile("s_waitcnt vmcnt(0)" ::: "memory");
    }
    MEMFENCE; __builtin_amdgcn_s_barrier(); MEMFENCE;

    f32x4 sf[2][4] = {};
    __builtin_amdgcn_s_setprio(1);
#pragma unroll
    for (int kk = 0; kk < 2; ++kk) {
      bf16x8 ak[4];
#pragma unroll
      for (int nbt = 0; nbt < 4; ++nbt) {
        const int br = nbt * 16 + lr;
        ak[nbt] = ldsv((const char*)curK + br * 128 + (((kk * 4 + lg) ^ (br & 7)) * 16));
      }
#pragma unroll
      for (int mbt = 0; mbt < 2; ++mbt)
#pragma unroll
        for (int nbt = 0; nbt < 4; ++nbt)
          sf[mbt][nbt] = mfma16(ak[nbt], qf[mbt][kk], sf[mbt][nbt]);
    }
    __builtin_amdgcn_s_setprio(0);

    if (kv0 + 64 > len) {
#pragma unroll
      for (int nbt = 0; nbt < 4; ++nbt)
#pragma unroll
        for (int jr = 0; jr < 4; ++jr)
          if (kv0 + nbt * 16 + lg * 4 + jr >= len) {
            sf[0][nbt][jr] = NEG;
            sf[1][nbt][jr] = NEG;
          }
    }

    float rm[2];
#pragma unroll
    for (int mbt = 0; mbt < 2; ++mbt) {
      f32x4 m4 = sf[mbt][0];
      m4 = __builtin_elementwise_max(m4, sf[mbt][1]);
      m4 = __builtin_elementwise_max(m4, sf[mbt][2]);
      m4 = __builtin_elementwise_max(m4, sf[mbt][3]);
      float m0 = fmaxf(fmaxf(m4[0], m4[1]), fmaxf(m4[2], m4[3]));
      m0 = fmaxf(m0, __shfl_xor(m0, 16, 64));
      m0 = fmaxf(m0, __shfl_xor(m0, 32, 64));
      rm[mbt] = m0;
    }
    const bool need = (rm[0] > mrun[0] + 3.f) || (rm[1] > mrun[1] + 3.f);
    if (__any(need)) {
#pragma unroll
      for (int mbt = 0; mbt < 2; ++mbt) {
        const float mnew = fmaxf(mrun[mbt], rm[mbt]);
        const float corr = __builtin_amdgcn_exp2f(mrun[mbt] - mnew);
        mrun[mbt] = mnew;
        ssum[mbt] *= corr;
#pragma unroll
        for (int nbt2 = 0; nbt2 < 4; ++nbt2) o[nbt2][mbt] *= corr;
      }
    }
    unsigned int W0[2][4], W1[2][4];
#pragma unroll
    for (int mbt = 0; mbt < 2; ++mbt) {
      f32x4 ts = {0.f, 0.f, 0.f, 0.f};
#pragma unroll
      for (int nbt = 0; nbt < 4; ++nbt) {
        f32x4 pe;
#pragma unroll
        for (int jr = 0; jr < 4; ++jr)
          pe[jr] = __builtin_amdgcn_exp2f(sf[mbt][nbt][jr] - mrun[mbt]);
        ts += pe;
        W0[mbt][nbt] = cvt_pk_bf16(pe[0], pe[1]);
        W1[mbt][nbt] = cvt_pk_bf16(pe[2], pe[3]);
      }
      ssum[mbt] += (ts[0] + ts[1]) + (ts[2] + ts[3]);
    }

#pragma unroll
    for (int c = 0; c < 2; ++c) {
      bf16x8 vf[4], pb[2];
#pragma unroll
      for (int nbt2 = 0; nbt2 < 4; ++nbt2) {
        const int vr = nbt2 * 16 + lr;
        vf[nbt2] = ldsv((const char*)curV + vr * 128 + (((c * 4 + lg) ^ (vr & 7)) * 16));
      }
#pragma unroll
      for (int mbt = 0; mbt < 2; ++mbt) {
        const unsigned int selW0 = (lg & 2) ? W0[mbt][2 * c + 1] : W0[mbt][2 * c];
        const unsigned int selW1 = (lg & 2) ? W1[mbt][2 * c + 1] : W1[mbt][2 * c];
        u32x4 bw;
        bw[0] = __shfl((int)selW0, srcA, 64);
        bw[1] = __shfl((int)selW1, srcA, 64);
        bw[2] = __shfl((int)selW0, srcB, 64);
        bw[3] = __shfl((int)selW1, srcB, 64);
        pb[mbt] = __builtin_bit_cast(bf16x8, bw);
      }
      __builtin_amdgcn_s_setprio(1);
#pragma unroll
      for (int nbt2 = 0; nbt2 < 4; ++nbt2)
#pragma unroll
        for (int mbt = 0; mbt < 2; ++mbt)
          o[nbt2][mbt] = mfma16(vf[nbt2], pb[mbt], o[nbt2][mbt]);
      __builtin_amdgcn_s_setprio(0);
    }

    asm volatile("s_waitcnt lgkmcnt(0)" ::: "memory");
    MEMFENCE; __builtin_amdgcn_s_barrier(); MEMFENCE;
    short* tk = curK; curK = nxtK; nxtK = tk;
    short* tv = curV; curV = nxtV; nxtV = tv;
  }

  float inv[2];
#pragma unroll
  for (int mbt = 0; mbt < 2; ++mbt) {
    float s = ssum[mbt];
    s += __shfl_xor(s, 16, 64);
    s += __shfl_xor(s, 32, 64);
    inv[mbt] = 1.f / s;
  }
  char* eb = (char*)sK + w * 4352;   // 32 rows x 68 shorts (136 B stride)
#pragma unroll
  for (int mbt = 0; mbt < 2; ++mbt)
#pragma unroll
    for (int nbt2 = 0; nbt2 < 4; ++nbt2)
#pragma unroll
      for (int jr = 0; jr < 4; ++jr)
        *(short*)(eb + (mbt * 16 + lr) * 136 + (nbt2 * 16 + lg * 4 + jr) * 2) =
            (short)f2b(o[nbt2][mbt][jr] * inv[mbt]);
  asm volatile("s_waitcnt lgkmcnt(0)" ::: "memory");
  __builtin_amdgcn_sched_barrier(0);
  const int qi = l >> 1, half = l & 1;
#pragma unroll
  for (int i = 0; i < 4; ++i) {
    s16x8 v = *(const s16x8*)(eb + qi * 136 + half * 64 + i * 16);
    *(s16x8*)((short*)ctx + (size_t)(b * 2048 + q0 + qi) * 1024 + h * 64 + half * 32 + i * 8) = v;
  }
}

// ------------------------------------------------------------------- launch
extern "C" void kernel_launch(void* const* d_in, const int* in_sizes, int n_in,
                              void* d_out, int out_size, void* d_ws, size_t ws_size,
                              hipStream_t stream)
{
  const float* x     = (const float*)d_in[0];
  const int*   lens  = (const int*)d_in[2];
  const float* Wq    = (const float*)d_in[3];
  const float* bq    = (const float*)d_in[4];
  const float* Wkv   = (const float*)d_in[5];
  const float* bkv   = (const float*)d_in[6];
  const float* Wo    = (const float*)d_in[7];
  const float* bo    = (const float*)d_in[8];
  const float* gamma = (const float*)d_in[9];
  const float* beta  = (const float*)d_in[10];
  float* out = (float*)d_out;

  char* ws = (char*)d_ws;
  __hip_bfloat16* ln  = (__hip_bfloat16*)(ws);
  __hip_bfloat16* qkv = (__hip_bfloat16*)(ws + ((size_t)16 << 20));
  __hip_bfloat16* vt  = (__hip_bfloat16*)(ws + ((size_t)64 << 20));
  __hip_bfloat16* ctx = (__hip_bfloat16*)(ws + ((size_t)80 << 20));
  __hip_bfloat16* wt  = (__hip_bfloat16*)(ws + ((size_t)96 << 20));
  __hip_bfloat16* wot = (__hip_bfloat16*)(ws + ((size_t)102 << 20));

  ln_kernel<<<dim3(8192), dim3(256), 0, stream>>>(x, gamma, beta, ln);
  wconv<<<dim3(16, 16), dim3(256), 0, stream>>>(Wq, 1024, wt);
  wconv<<<dim3(16, 32), dim3(256), 0, stream>>>(Wkv, 2048, wt + (size_t)1024 * 1024);
  wconv<<<dim3(16, 16), dim3(256), 0, stream>>>(Wo, 1024, wot);
  gemm8<<<dim3(384), dim3(512), 0, stream>>>(ln, wt, bq, bkv, 1024, qkv);
  vtrans<<<dim3(32, 64), dim3(256), 0, stream>>>(qkv, vt);
  attn_kernel<<<dim3(16, 64), dim3(256), 0, stream>>>(qkv, vt, lens, ctx);
  gemm_bt<<<dim3(8, 64), dim3(256), 0, stream>>>(ctx, wot, bo, ln, out);
}

// Round 6
// 181.119 us; speedup vs baseline: 1.9385x; 1.0431x over previous
//
#include <hip/hip_runtime.h>
#include <hip/hip_bf16.h>
#include <cstdint>
#include <cmath>

// MultiHeadAttention_38946763440365 : B=4 S=2048 D=1024 H=16 DQ=DV=64
// LN -> QKV gemm (256x128, BK=64, 3-buf counted-vmcnt pipeline) -> flash attn
// (swapped-QK in-register softmax) -> out gemm (+bias+residual)
// Workspace map (bytes):
//   [0,16M)    ln    bf16 [8192][1024]   (also the residual)
//   [16M,64M)  qkv   bf16 [8192][3072]   (Q | K | V)
//   [64M,80M)  vt    bf16 [64][64][2048] (V transposed per (b,h): [dv][s])
//   [80M,96M)  ctx   bf16 [8192][1024]
//   [96M,102M) wt    bf16 [3072][1024]   (Wq^T | Wkv^T)
//   [102M,104M)wot   bf16 [1024][1024]   (Wo^T)

#define DEV static __device__ __forceinline__

typedef float  f32x4 __attribute__((ext_vector_type(4)));
typedef short  s16x8 __attribute__((ext_vector_type(8)));
typedef short  s16x4 __attribute__((ext_vector_type(4)));
typedef __bf16 bf16x8 __attribute__((ext_vector_type(8)));
typedef unsigned int u32x4 __attribute__((ext_vector_type(4)));

DEV void gload_lds16(const void* g, void* l) {
  __builtin_amdgcn_global_load_lds(
      (const __attribute__((address_space(1))) unsigned int*)g,
      (__attribute__((address_space(3))) unsigned int*)l, 16, 0, 0);
}

DEV bf16x8 ldsv(const void* p) {
  return __builtin_bit_cast(bf16x8, *(const s16x8*)p);
}

DEV f32x4 mfma16(bf16x8 a, bf16x8 b, f32x4 c) {
  return __builtin_amdgcn_mfma_f32_16x16x32_bf16(a, b, c, 0, 0, 0);
}

DEV unsigned short f2b(float f) {
  __hip_bfloat16 h = __float2bfloat16(f);
  return __builtin_bit_cast(unsigned short, h);
}

DEV unsigned int cvt_pk_bf16(float lo, float hi) {
  unsigned int r;
  asm("v_cvt_pk_bf16_f32 %0, %1, %2" : "=v"(r) : "v"(lo), "v"(hi));
  return r;
}

#define MEMFENCE asm volatile("" ::: "memory")

// ---------------------------------------------------------------- LayerNorm
__global__ __launch_bounds__(256) void ln_kernel(
    const float* __restrict__ x, const float* __restrict__ gamma,
    const float* __restrict__ beta, __hip_bfloat16* __restrict__ out)
{
  const int row = blockIdx.x, t = threadIdx.x;
  const float4 v = ((const float4*)(x + (size_t)row * 1024))[t];
  float s = v.x + v.y + v.z + v.w;
  float q = v.x * v.x + v.y * v.y + v.z * v.z + v.w * v.w;
#pragma unroll
  for (int m = 1; m < 64; m <<= 1) { s += __shfl_xor(s, m, 64); q += __shfl_xor(q, m, 64); }
  __shared__ float red[8];
  if ((t & 63) == 0) { red[t >> 6] = s; red[4 + (t >> 6)] = q; }
  __syncthreads();
  s = red[0] + red[1] + red[2] + red[3];
  q = red[4] + red[5] + red[6] + red[7];
  const float mu = s * (1.f / 1024.f);
  const float var = q * (1.f / 1024.f) - mu * mu;
  const float rs = rsqrtf(var + 1e-3f);
  const float4 g = ((const float4*)gamma)[t];
  const float4 bt = ((const float4*)beta)[t];
  s16x4 o;
  o[0] = (short)f2b((v.x - mu) * rs * g.x + bt.x);
  o[1] = (short)f2b((v.y - mu) * rs * g.y + bt.y);
  o[2] = (short)f2b((v.z - mu) * rs * g.z + bt.z);
  o[3] = (short)f2b((v.w - mu) * rs * g.w + bt.w);
  *(s16x4*)((short*)out + (size_t)row * 1024 + t * 4) = o;
}

// ------------------------------------------- weight convert + transpose (K=1024)
__global__ __launch_bounds__(256) void wconv(
    const float* __restrict__ W, int N, __hip_bfloat16* __restrict__ Wt)
{
  __shared__ float tile[64][65];
  const int t = threadIdx.x;
  const int k0 = blockIdx.x * 64, n0 = blockIdx.y * 64;
#pragma unroll
  for (int p = 0; p < 4; ++p) {
    int r = p * 16 + (t >> 4), c4 = (t & 15) * 4;
    float4 v = *(const float4*)(W + (size_t)(k0 + r) * N + n0 + c4);
    tile[r][c4] = v.x; tile[r][c4 + 1] = v.y; tile[r][c4 + 2] = v.z; tile[r][c4 + 3] = v.w;
  }
  __syncthreads();
#pragma unroll
  for (int p = 0; p < 4; ++p) {
    int n = p * 16 + (t >> 4), kc = (t & 15) * 4;
    s16x4 o;
    o[0] = (short)f2b(tile[kc][n]);     o[1] = (short)f2b(tile[kc + 1][n]);
    o[2] = (short)f2b(tile[kc + 2][n]); o[3] = (short)f2b(tile[kc + 3][n]);
    *(s16x4*)((short*)Wt + (size_t)(n0 + n) * 1024 + k0 + kc) = o;
  }
}

// ---------------------------------- QKV GEMM: 256x128 tile, BK=64, 3-buffer
// pipeline with counted vmcnt (T3/T4) + setprio (T5). 768 blocks = 3/CU exact.
// Per K-tile: 2 phases {8 ds_read + 3 gload_lds(t+2) -> bar -> lgkm0 -> prio1
// 16 MFMA prio0 -> [vmcnt(6) at phase 1] -> bar}. vmcnt never 0 mid-loop.
__global__ __launch_bounds__(512, 2) void gemmP(
    const __hip_bfloat16* __restrict__ A, const __hip_bfloat16* __restrict__ Bt,
    const float* __restrict__ bias0, const float* __restrict__ bias1, int split,
    __hip_bfloat16* __restrict__ outb)
{
  __shared__ __align__(16) short sA[3 * 16384];  // 3 x [256 rows][64 k]
  __shared__ __align__(16) short sB[3 * 8192];   // 3 x [128 rows][64 k]
  const int t = threadIdx.x, l = t & 63, w = t >> 6;
  const int wr = w >> 1, wc = w & 1, lr = l & 15, lg = l >> 4;
  int bid = blockIdx.x;
  bid = (bid & 7) * 96 + (bid >> 3);             // XCD-chunked, 768 % 8 == 0
  const int bx = bid % 24, by = bid / 24;        // 24 col-tiles x 32 row-tiles
  const int row0 = by * 256, col0 = bx * 128;
  const int NT = 16;

  f32x4 acc[4][4] = {};

  // A tile 32KB = 4 passes; B tile 16KB = 2 passes. half selects 2A+1B each.
  auto stageA2 = [&](int buf, int kt, int half) {
#pragma unroll
    for (int p = 0; p < 2; ++p) {
      const int L = (half * 2 + p) * 8192 + t * 16;
      const int r = L >> 7, c = (L >> 4) & 7;
      const int j = c ^ (r & 7);                 // inverse swizzle on source
      gload_lds16((const char*)A + ((size_t)(row0 + r) * 1024 + kt + j * 8) * 2,
                  (char*)sA + buf * 32768 + L);
    }
  };
  auto stageB1 = [&](int buf, int kt, int half) {
    const int L = half * 8192 + t * 16;
    const int r = L >> 7, c = (L >> 4) & 7;
    const int j = c ^ (r & 7);
    gload_lds16((const char*)Bt + ((size_t)(col0 + r) * 1024 + kt + j * 8) * 2,
                (char*)sB + buf * 16384 + L);
  };

  // prologue: stage tiles 0 and 1 (6 loads each)
  stageA2(0, 0, 0);  stageB1(0, 0, 0);  stageA2(0, 0, 1);  stageB1(0, 0, 1);
  stageA2(1, 64, 0); stageB1(1, 64, 0); stageA2(1, 64, 1); stageB1(1, 64, 1);
  asm volatile("s_waitcnt vmcnt(6)" ::: "memory");   // tile 0 landed, tile 1 in flight
  MEMFENCE; __builtin_amdgcn_s_barrier(); MEMFENCE;

#pragma unroll 1
  for (int ti = 0; ti < NT; ++ti) {
    const char* bA = (const char*)sA + (ti % 3) * 32768;
    const char* bB = (const char*)sB + (ti % 3) * 16384;
    const int nx = (ti + 2) % 3;
    const bool pre = (ti + 2 < NT);
#pragma unroll
    for (int kk = 0; kk < 2; ++kk) {
      bf16x8 af[4], bfr[4];
#pragma unroll
      for (int nb = 0; nb < 4; ++nb) {
        const int br = wc * 64 + nb * 16 + lr;
        bfr[nb] = ldsv(bB + br * 128 + (((kk * 4 + lg) ^ (br & 7)) * 16));
      }
#pragma unroll
      for (int mb = 0; mb < 4; ++mb) {
        const int ar = wr * 64 + mb * 16 + lr;
        af[mb] = ldsv(bA + ar * 128 + (((kk * 4 + lg) ^ (ar & 7)) * 16));
      }
      if (pre) { stageA2(nx, (ti + 2) * 64, kk); stageB1(nx, (ti + 2) * 64, kk); }
      MEMFENCE; __builtin_amdgcn_s_barrier(); MEMFENCE;
      asm volatile("s_waitcnt lgkmcnt(0)" ::: "memory");
      __builtin_amdgcn_s_setprio(1);
#pragma unroll
      for (int mb = 0; mb < 4; ++mb)
#pragma unroll
        for (int nb = 0; nb < 4; ++nb)
          acc[mb][nb] = mfma16(af[mb], bfr[nb], acc[mb][nb]);
      __builtin_amdgcn_s_setprio(0);
      if (kk == 1) {
        if (pre) asm volatile("s_waitcnt vmcnt(6)" ::: "memory");   // t+1 landed
        else     asm volatile("s_waitcnt vmcnt(0)" ::: "memory");
      }
      MEMFENCE; __builtin_amdgcn_s_barrier(); MEMFENCE;
    }
  }

#pragma unroll
  for (int mb = 0; mb < 4; ++mb) {
    const int rbase = row0 + wr * 64 + mb * 16 + lg * 4;
#pragma unroll
    for (int nb = 0; nb < 4; ++nb) {
      const int col = col0 + wc * 64 + nb * 16 + lr;
      const float bias = (col < split) ? bias0[col] : bias1[col - split];
#pragma unroll
      for (int jr = 0; jr < 4; ++jr)
        outb[(size_t)(rbase + jr) * 3072 + col] = __float2bfloat16(acc[mb][nb][jr] + bias);
    }
  }
}

// ------------------------------------------------------- GEMM: out proj (+resid)
__global__ __launch_bounds__(256, 2) void gemm_bt(
    const __hip_bfloat16* __restrict__ A, const __hip_bfloat16* __restrict__ Bt,
    const float* __restrict__ bias0,
    const __hip_bfloat16* __restrict__ resid, float* __restrict__ outf)
{
  __shared__ __align__(16) short sA[128 * 64];
  __shared__ __align__(16) short sB[128 * 64];
  const int t = threadIdx.x, l = t & 63, w = t >> 6;
  const int wr = w >> 1, wc = w & 1, lr = l & 15, lg = l >> 4;
  const int row0 = blockIdx.y * 128, col0 = blockIdx.x * 128;
  f32x4 acc[4][4] = {};

  for (int kt = 0; kt < 1024; kt += 64) {
#pragma unroll
    for (int p = 0; p < 4; ++p) {
      const int L = p * 4096 + t * 16;
      const int r = L >> 7, c = ((L >> 4) & 7) ^ (r & 7);
      gload_lds16((const char*)A + ((size_t)(row0 + r) * 1024 + kt + c * 8) * 2, (char*)sA + L);
    }
#pragma unroll
    for (int p = 0; p < 4; ++p) {
      const int L = p * 4096 + t * 16;
      const int r = L >> 7, c = ((L >> 4) & 7) ^ (r & 7);
      gload_lds16((const char*)Bt + ((size_t)(col0 + r) * 1024 + kt + c * 8) * 2, (char*)sB + L);
    }
    __syncthreads();

    bf16x8 af[4][2], bfr[4][2];
#pragma unroll
    for (int mb = 0; mb < 4; ++mb) {
      const int ar = wr * 64 + mb * 16 + lr;
#pragma unroll
      for (int kk = 0; kk < 2; ++kk)
        af[mb][kk] = ldsv((const char*)sA + ar * 128 + (((kk * 4 + lg) ^ (ar & 7)) * 16));
    }
#pragma unroll
    for (int nb = 0; nb < 4; ++nb) {
      const int br = wc * 64 + nb * 16 + lr;
#pragma unroll
      for (int kk = 0; kk < 2; ++kk)
        bfr[nb][kk] = ldsv((const char*)sB + br * 128 + (((kk * 4 + lg) ^ (br & 7)) * 16));
    }
#pragma unroll
    for (int kk = 0; kk < 2; ++kk)
#pragma unroll
      for (int mb = 0; mb < 4; ++mb)
#pragma unroll
        for (int nb = 0; nb < 4; ++nb)
          acc[mb][nb] = mfma16(af[mb][kk], bfr[nb][kk], acc[mb][nb]);
    __syncthreads();
  }

#pragma unroll
  for (int mb = 0; mb < 4; ++mb) {
    const int rbase = row0 + wr * 64 + mb * 16 + lg * 4;
#pragma unroll
    for (int nb = 0; nb < 4; ++nb) {
      const int col = col0 + wc * 64 + nb * 16 + lr;
      const float bias = bias0[col];
#pragma unroll
      for (int jr = 0; jr < 4; ++jr) {
        const size_t idx = (size_t)(rbase + jr) * 1024 + col;
        outf[idx] = acc[mb][nb][jr] + bias + __bfloat162float(resid[idx]);
      }
    }
  }
}

// --------------------------------------- V transpose: qkv V-part -> [bh][dv][s]
__global__ __launch_bounds__(256) void vtrans(
    const __hip_bfloat16* __restrict__ qkv, __hip_bfloat16* __restrict__ vt)
{
  __shared__ __align__(16) short tile[64][72];
  const int t = threadIdx.x;
  const int s0 = blockIdx.x * 64;
  const int bh = blockIdx.y, b = bh >> 4, h = bh & 15;
#pragma unroll
  for (int p = 0; p < 2; ++p) {
    int idx = p * 256 + t;
    int r = idx >> 3, c = idx & 7;
    s16x8 vv = *(const s16x8*)((const short*)qkv +
        (size_t)(b * 2048 + s0 + r) * 3072 + 2048 + h * 64 + c * 8);
    *(s16x8*)((char*)tile + r * 144 + c * 16) = vv;
  }
  __syncthreads();
  const int dv = t >> 2, sc = (t & 3) * 16;
  s16x8 a, bvec;
#pragma unroll
  for (int e = 0; e < 8; ++e) a[e] = tile[sc + e][dv];
#pragma unroll
  for (int e = 0; e < 8; ++e) bvec[e] = tile[sc + 8 + e][dv];
  short* dst = (short*)vt + (size_t)(bh * 64 + dv) * 2048 + s0 + sc;
  *(s16x8*)dst = a;
  *(s16x8*)(dst + 8) = bvec;
}

// ----------------------------------------------------------- flash attention
// grid (S/128, B*H); 4 waves x 32 q-rows; KVBLK=64. (R3-verified structure)
__global__ __launch_bounds__(256, 4) void attn_kernel(
    const __hip_bfloat16* __restrict__ qkv, const __hip_bfloat16* __restrict__ vt,
    const int* __restrict__ lens, __hip_bfloat16* __restrict__ ctx)
{
  __shared__ __align__(16) short sK[2][64 * 64];
  __shared__ __align__(16) short sV[2][64 * 64];
  const int t = threadIdx.x, l = t & 63, w = t >> 6;
  const int lr = l & 15, lg = l >> 4;
  const int bh = blockIdx.y, b = bh >> 4, h = bh & 15;
  const int q0 = blockIdx.x * 128 + w * 32;
  const int len = lens[b];
  const float NEG = -__builtin_inff();
  const float QSC = 0.18033688f;  // 0.125 * log2(e)

  bf16x8 qf[2][2];
#pragma unroll
  for (int mbt = 0; mbt < 2; ++mbt)
#pragma unroll
    for (int kk = 0; kk < 2; ++kk) {
      bf16x8 r = ldsv((const char*)qkv +
          ((size_t)(b * 2048 + q0 + mbt * 16 + lr) * 3072 + h * 64 + kk * 32 + lg * 8) * 2);
#pragma unroll
      for (int e = 0; e < 8; ++e) qf[mbt][kk][e] = (__bf16)((float)r[e] * QSC);
    }

  f32x4 o[4][2] = {};
  float mrun[2] = {NEG, NEG}, ssum[2] = {0.f, 0.f};

  auto stage = [&](short* dK, short* dV, int kv0) {
#pragma unroll
    for (int p = 0; p < 2; ++p) {
      const int L = p * 4096 + t * 16;
      const int r = L >> 7, c = ((L >> 4) & 7) ^ (r & 7);
      gload_lds16((const char*)qkv +
          ((size_t)(b * 2048 + kv0 + r) * 3072 + 1024 + h * 64 + c * 8) * 2, (char*)dK + L);
    }
#pragma unroll
    for (int p = 0; p < 2; ++p) {
      const int L = p * 4096 + t * 16;
      const int r = L >> 7, c = ((L >> 4) & 7) ^ (r & 7);
      gload_lds16((const char*)vt +
          ((size_t)(bh * 64 + r) * 2048 + kv0 + c * 8) * 2, (char*)dV + L);
    }
  };

  const int nt = (len + 63) >> 6;
  short* curK = sK[0]; short* nxtK = sK[1];
  short* curV = sV[0]; short* nxtV = sV[1];
  stage(curK, curV, 0);

  const int srcA = (lg & 1) * 32 + lr;
  const int srcB = srcA + 16;

  for (int ti = 0; ti < nt; ++ti) {
    const int kv0 = ti * 64;
    if (ti + 1 < nt) {
      stage(nxtK, nxtV, kv0 + 64);
      asm volatile("s_waitcnt vmcnt(4)" ::: "memory");
    } else {
      asm volatile("s_waitcnt vmcnt(0)" ::: "memory");
    }
    MEMFENCE; __builtin_amdgcn_s_barrier(); MEMFENCE;

    f32x4 sf[2][4] = {};
    __builtin_amdgcn_s_setprio(1);
#pragma unroll
    for (int kk = 0; kk < 2; ++kk) {
      bf16x8 ak[4];
#pragma unroll
      for (int nbt = 0; nbt < 4; ++nbt) {
        const int br = nbt * 16 + lr;
        ak[nbt] = ldsv((const char*)curK + br * 128 + (((kk * 4 + lg) ^ (br & 7)) * 16));
      }
#pragma unroll
      for (int mbt = 0; mbt < 2; ++mbt)
#pragma unroll
        for (int nbt = 0; nbt < 4; ++nbt)
          sf[mbt][nbt] = mfma16(ak[nbt], qf[mbt][kk], sf[mbt][nbt]);
    }
    __builtin_amdgcn_s_setprio(0);

    if (kv0 + 64 > len) {
#pragma unroll
      for (int nbt = 0; nbt < 4; ++nbt)
#pragma unroll
        for (int jr = 0; jr < 4; ++jr)
          if (kv0 + nbt * 16 + lg * 4 + jr >= len) {
            sf[0][nbt][jr] = NEG;
            sf[1][nbt][jr] = NEG;
          }
    }

    float rm[2];
#pragma unroll
    for (int mbt = 0; mbt < 2; ++mbt) {
      f32x4 m4 = sf[mbt][0];
      m4 = __builtin_elementwise_max(m4, sf[mbt][1]);
      m4 = __builtin_elementwise_max(m4, sf[mbt][2]);
      m4 = __builtin_elementwise_max(m4, sf[mbt][3]);
      float m0 = fmaxf(fmaxf(m4[0], m4[1]), fmaxf(m4[2], m4[3]));
      m0 = fmaxf(m0, __shfl_xor(m0, 16, 64));
      m0 = fmaxf(m0, __shfl_xor(m0, 32, 64));
      rm[mbt] = m0;
    }
    const bool need = (rm[0] > mrun[0] + 3.f) || (rm[1] > mrun[1] + 3.f);
    if (__any(need)) {
#pragma unroll
      for (int mbt = 0; mbt < 2; ++mbt) {
        const float mnew = fmaxf(mrun[mbt], rm[mbt]);
        const float corr = __builtin_amdgcn_exp2f(mrun[mbt] - mnew);
        mrun[mbt] = mnew;
        ssum[mbt] *= corr;
#pragma unroll
        for (int nbt2 = 0; nbt2 < 4; ++nbt2) o[nbt2][mbt] *= corr;
      }
    }
    unsigned int W0[2][4], W1[2][4];
#pragma unroll
    for (int mbt = 0; mbt < 2; ++mbt) {
      f32x4 ts = {0.f, 0.f, 0.f, 0.f};
#pragma unroll
      for (int nbt = 0; nbt < 4; ++nbt) {
        f32x4 pe;
#pragma unroll
        for (int jr = 0; jr < 4; ++jr)
          pe[jr] = __builtin_amdgcn_exp2f(sf[mbt][nbt][jr] - mrun[mbt]);
        ts += pe;
        W0[mbt][nbt] = cvt_pk_bf16(pe[0], pe[1]);
        W1[mbt][nbt] = cvt_pk_bf16(pe[2], pe[3]);
      }
      ssum[mbt] += (ts[0] + ts[1]) + (ts[2] + ts[3]);
    }

#pragma unroll
    for (int c = 0; c < 2; ++c) {
      bf16x8 vf[4], pb[2];
#pragma unroll
      for (int nbt2 = 0; nbt2 < 4; ++nbt2) {
        const int vr = nbt2 * 16 + lr;
        vf[nbt2] = ldsv((const char*)curV + vr * 128 + (((c * 4 + lg) ^ (vr & 7)) * 16));
      }
#pragma unroll
      for (int mbt = 0; mbt < 2; ++mbt) {
        const unsigned int selW0 = (lg & 2) ? W0[mbt][2 * c + 1] : W0[mbt][2 * c];
        const unsigned int selW1 = (lg & 2) ? W1[mbt][2 * c + 1] : W1[mbt][2 * c];
        u32x4 bw;
        bw[0] = __shfl((int)selW0, srcA, 64);
        bw[1] = __shfl((int)selW1, srcA, 64);
        bw[2] = __shfl((int)selW0, srcB, 64);
        bw[3] = __shfl((int)selW1, srcB, 64);
        pb[mbt] = __builtin_bit_cast(bf16x8, bw);
      }
      __builtin_amdgcn_s_setprio(1);
#pragma unroll
      for (int nbt2 = 0; nbt2 < 4; ++nbt2)
#pragma unroll
        for (int mbt = 0; mbt < 2; ++mbt)
          o[nbt2][mbt] = mfma16(vf[nbt2], pb[mbt], o[nbt2][mbt]);
      __builtin_amdgcn_s_setprio(0);
    }

    asm volatile("s_waitcnt lgkmcnt(0)" ::: "memory");
    MEMFENCE; __builtin_amdgcn_s_barrier(); MEMFENCE;
    short* tk = curK; curK = nxtK; nxtK = tk;
    short* tv = curV; curV = nxtV; nxtV = tv;
  }

  float inv[2];
#pragma unroll
  for (int mbt = 0; mbt < 2; ++mbt) {
    float s = ssum[mbt];
    s += __shfl_xor(s, 16, 64);
    s += __shfl_xor(s, 32, 64);
    inv[mbt] = 1.f / s;
  }
  char* eb = (char*)sK + w * 4352;   // 32 rows x 68 shorts (136 B stride)
#pragma unroll
  for (int mbt = 0; mbt < 2; ++mbt)
#pragma unroll
    for (int nbt2 = 0; nbt2 < 4; ++nbt2)
#pragma unroll
      for (int jr = 0; jr < 4; ++jr)
        *(short*)(eb + (mbt * 16 + lr) * 136 + (nbt2 * 16 + lg * 4 + jr) * 2) =
            (short)f2b(o[nbt2][mbt][jr] * inv[mbt]);
  asm volatile("s_waitcnt lgkmcnt(0)" ::: "memory");
  __builtin_amdgcn_sched_barrier(0);
  const int qi = l >> 1, half = l & 1;
#pragma unroll
  for (int i = 0; i < 4; ++i) {
    s16x8 v = *(const s16x8*)(eb + qi * 136 + half * 64 + i * 16);
    *(s16x8*)((short*)ctx + (size_t)(b * 2048 + q0 + qi) * 1024 + h * 64 + half * 32 + i * 8) = v;
  }
}

// ------------------------------------------------------------------- launch
extern "C" void kernel_launch(void* const* d_in, const int* in_sizes, int n_in,
                              void* d_out, int out_size, void* d_ws, size_t ws_size,
                              hipStream_t stream)
{
  const float* x     = (const float*)d_in[0];
  const int*   lens  = (const int*)d_in[2];
  const float* Wq    = (const float*)d_in[3];
  const float* bq    = (const float*)d_in[4];
  const float* Wkv   = (const float*)d_in[5];
  const float* bkv   = (const float*)d_in[6];
  const float* Wo    = (const float*)d_in[7];
  const float* bo    = (const float*)d_in[8];
  const float* gamma = (const float*)d_in[9];
  const float* beta  = (const float*)d_in[10];
  float* out = (float*)d_out;

  char* ws = (char*)d_ws;
  __hip_bfloat16* ln  = (__hip_bfloat16*)(ws);
  __hip_bfloat16* qkv = (__hip_bfloat16*)(ws + ((size_t)16 << 20));
  __hip_bfloat16* vt  = (__hip_bfloat16*)(ws + ((size_t)64 << 20));
  __hip_bfloat16* ctx = (__hip_bfloat16*)(ws + ((size_t)80 << 20));
  __hip_bfloat16* wt  = (__hip_bfloat16*)(ws + ((size_t)96 << 20));
  __hip_bfloat16* wot = (__hip_bfloat16*)(ws + ((size_t)102 << 20));

  ln_kernel<<<dim3(8192), dim3(256), 0, stream>>>(x, gamma, beta, ln);
  wconv<<<dim3(16, 16), dim3(256), 0, stream>>>(Wq, 1024, wt);
  wconv<<<dim3(16, 32), dim3(256), 0, stream>>>(Wkv, 2048, wt + (size_t)1024 * 1024);
  wconv<<<dim3(16, 16), dim3(256), 0, stream>>>(Wo, 1024, wot);
  gemmP<<<dim3(768), dim3(512), 0, stream>>>(ln, wt, bq, bkv, 1024, qkv);
  vtrans<<<dim3(32, 64), dim3(256), 0, stream>>>(qkv, vt);
  attn_kernel<<<dim3(16, 64), dim3(256), 0, stream>>>(qkv, vt, lens, ctx);
  gemm_bt<<<dim3(8, 64), dim3(256), 0, stream>>>(ctx, wot, bo, ln, out);
}